// Round 3
// baseline (2726.744 us; speedup 1.0000x reference)
//
#include <hip/hip_runtime.h>
#include <hip/hip_bf16.h>
#include <math.h>

#define N_NODES 50000
#define N_EDGES 800000
#define EPRIME  (N_EDGES + N_NODES)   // edges + self loops
#define HEADS 8
#define CH 64
#define FDIM 512                       // HEADS*CH

typedef unsigned short ushort_t;

__device__ __forceinline__ float bf2f(unsigned short u) {
  union { unsigned int i; float f; } v; v.i = ((unsigned int)u) << 16; return v.f;
}
__device__ __forceinline__ unsigned short f2bf(float f) {
  union { float f; unsigned int i; } v; v.f = f;
  unsigned int x = v.i;
  return (unsigned short)((x + 0x7fffu + ((x >> 16) & 1u)) >> 16);  // RNE
}
// dual-dtype load/store for RAW input tensors (dtype detected at runtime)
__device__ __forceinline__ float ldf(const void* p, size_t idx, int isf32) {
  return isf32 ? ((const float*)p)[idx] : bf2f(((const ushort_t*)p)[idx]);
}
__device__ __forceinline__ void stf(void* p, size_t idx, float v, int isf32) {
  if (isf32) ((float*)p)[idx] = v;
  else       ((ushort_t*)p)[idx] = f2bf(v);
}
__device__ __forceinline__ float leakyf(float v) { return v >= 0.f ? v : 0.2f * v; }
__device__ __forceinline__ float eluf(float v)   { return v > 0.f ? v : expm1f(v); }

// ---------------- dtype detector ----------------
// Wn holds 192 weights ~N(0,0.01). Interpreted as bf16 pairs: a true bf16
// buffer has ~0 exponent-extreme values; a true f32 buffer's low halves have
// uniform-random exponents -> ~90% extreme. extreme>=20 => f32.
__global__ void detect_dtype(const void* Wn, int* flag) {
  if (blockIdx.x == 0 && threadIdx.x == 0) {
    const ushort_t* u = (const ushort_t*)Wn;
    int extreme = 0;
    for (int i = 0; i < 384; ++i) {
      float v = fabsf(bf2f(u[i]));
      if (v != 0.f && (v > 16.f || v < 6.1e-5f)) extreme++;
    }
    *flag = (extreme >= 20) ? 1 : 0;
  }
}

// ---------------- CSR build ----------------
__global__ void init_deg(int* deg, int* fill) {
  int n = blockIdx.x * blockDim.x + threadIdx.x;
  if (n < N_NODES) { deg[n] = 1; fill[n] = 0; }   // 1 = self loop
}

__global__ void count_edges(const int* __restrict__ ei, int* deg) {
  int e = blockIdx.x * blockDim.x + threadIdx.x;
  if (e < N_EDGES) atomicAdd(&deg[ei[N_EDGES + e]], 1);
}

// single wave, per-thread sequential chunks + one shfl scan
__global__ void scan64(const int* __restrict__ deg, int* __restrict__ rowptr) {
  const int CHUNK = (N_NODES + 63) / 64;   // 782
  int t = threadIdx.x;                      // 0..63, one wave
  int lo = t * CHUNK;
  int hi = lo + CHUNK; if (hi > N_NODES) hi = N_NODES;
  int s = 0;
  for (int i = lo; i < hi; ++i) s += deg[i];
  int inc = s;
  #pragma unroll
  for (int off = 1; off < 64; off <<= 1) {
    int u = __shfl_up(inc, off);
    if (t >= off) inc += u;
  }
  int run = inc - s;                        // exclusive prefix of chunk sums
  for (int i = lo; i < hi; ++i) { rowptr[i] = run; run += deg[i]; }
  if (t == 63) rowptr[N_NODES] = run;       // total = EPRIME
}

__global__ void fill_csr(const int* __restrict__ ei, const int* __restrict__ rowptr,
                         int* fill, int* __restrict__ csr_src) {
  int e = blockIdx.x * blockDim.x + threadIdx.x;
  if (e >= EPRIME) return;
  int s, d;
  if (e < N_EDGES) { s = ei[e]; d = ei[N_EDGES + e]; }
  else             { s = d = e - N_EDGES; }
  int pos = rowptr[d] + atomicAdd(&fill[d], 1);
  csr_src[pos] = s;
}

// ---------------- node encoder ----------------
__global__ void encode_h(const void* __restrict__ x, const void* __restrict__ Wn,
                         const void* __restrict__ bn, ushort_t* __restrict__ h,
                         const int* __restrict__ dflag) {
  int isf32 = *dflag;
  int tid = blockIdx.x * blockDim.x + threadIdx.x;
  if (tid >= N_NODES * 64) return;
  int n = tid >> 6, j = tid & 63;
  float x0 = ldf(x, n * 3 + 0, isf32), x1 = ldf(x, n * 3 + 1, isf32), x2 = ldf(x, n * 3 + 2, isf32);
  float v = x0 * ldf(Wn, j, isf32) + x1 * ldf(Wn, 64 + j, isf32)
          + x2 * ldf(Wn, 128 + j, isf32) + ldf(bn, j, isf32);
  h[tid] = f2bf(v);
}

// ---------------- GEMM: C[M,cols] = A[M,K] @ B[boff + k, col], fp32 accum ----
// A: ws bf16. B: RAW input weight (dual dtype), boff = element row-offset.
// grid.x = ceil(M/64), grid.y = cols/64
__global__ __launch_bounds__(256) void gemm64(
    const ushort_t* __restrict__ A, const void* __restrict__ B, size_t boff,
    ushort_t* __restrict__ C, int M, int K, int ldb, int ldc,
    const int* __restrict__ dflag)
{
  int isf32 = *dflag;
  __shared__ float As[16][65];
  __shared__ float Bs[16][64];
  int tid = threadIdx.x;
  int tx = tid & 15, ty = tid >> 4;
  int row0 = blockIdx.x * 64, col0 = blockIdx.y * 64;
  float acc[4][4];
  #pragma unroll
  for (int i = 0; i < 4; ++i)
    #pragma unroll
    for (int j = 0; j < 4; ++j) acc[i][j] = 0.f;

  int arow = tid >> 2;        // 0..63
  int ak   = (tid & 3) * 4;   // 0,4,8,12
  int brow = tid >> 4;        // 0..15
  int bcol = (tid & 15) * 4;

  for (int k0 = 0; k0 < K; k0 += 16) {
    ushort4 av = make_ushort4(0, 0, 0, 0);
    int grow = row0 + arow;
    if (grow < M) av = *(const ushort4*)(A + (size_t)grow * K + k0 + ak);
    As[ak + 0][arow] = bf2f(av.x);
    As[ak + 1][arow] = bf2f(av.y);
    As[ak + 2][arow] = bf2f(av.z);
    As[ak + 3][arow] = bf2f(av.w);
    size_t bidx = boff + (size_t)(k0 + brow) * ldb + col0 + bcol;
    if (isf32) {
      float4 bv = *(const float4*)((const float*)B + bidx);
      Bs[brow][bcol + 0] = bv.x;
      Bs[brow][bcol + 1] = bv.y;
      Bs[brow][bcol + 2] = bv.z;
      Bs[brow][bcol + 3] = bv.w;
    } else {
      ushort4 bv = *(const ushort4*)((const ushort_t*)B + bidx);
      Bs[brow][bcol + 0] = bf2f(bv.x);
      Bs[brow][bcol + 1] = bf2f(bv.y);
      Bs[brow][bcol + 2] = bf2f(bv.z);
      Bs[brow][bcol + 3] = bf2f(bv.w);
    }
    __syncthreads();
    #pragma unroll
    for (int k = 0; k < 16; ++k) {
      float a0 = As[k][ty * 4 + 0], a1 = As[k][ty * 4 + 1];
      float a2 = As[k][ty * 4 + 2], a3 = As[k][ty * 4 + 3];
      float b0 = Bs[k][tx * 4 + 0], b1 = Bs[k][tx * 4 + 1];
      float b2 = Bs[k][tx * 4 + 2], b3 = Bs[k][tx * 4 + 3];
      acc[0][0] += a0 * b0; acc[0][1] += a0 * b1; acc[0][2] += a0 * b2; acc[0][3] += a0 * b3;
      acc[1][0] += a1 * b0; acc[1][1] += a1 * b1; acc[1][2] += a1 * b2; acc[1][3] += a1 * b3;
      acc[2][0] += a2 * b0; acc[2][1] += a2 * b1; acc[2][2] += a2 * b2; acc[2][3] += a2 * b3;
      acc[3][0] += a3 * b0; acc[3][1] += a3 * b1; acc[3][2] += a3 * b2; acc[3][3] += a3 * b3;
    }
    __syncthreads();
  }
  #pragma unroll
  for (int i = 0; i < 4; ++i) {
    int grow = row0 + ty * 4 + i;
    if (grow < M) {
      ushort4 o;
      o.x = f2bf(acc[i][0]); o.y = f2bf(acc[i][1]);
      o.z = f2bf(acc[i][2]); o.w = f2bf(acc[i][3]);
      *(ushort4*)(C + (size_t)grow * ldc + col0 + tx * 4) = o;
    }
  }
}

// ---------------- attention coefficients ----------------
__global__ void attn_coef(const ushort_t* __restrict__ g, const void* __restrict__ a_s,
                          const void* __restrict__ a_d, float* __restrict__ asrc,
                          float* __restrict__ adst, const int* __restrict__ dflag) {
  int isf32 = *dflag;
  int tid = blockIdx.x * blockDim.x + threadIdx.x;
  if (tid >= N_NODES * HEADS) return;
  int n = tid >> 3, h = tid & 7;
  const ushort_t* gr = g + (size_t)n * FDIM + h * CH;
  float ss = 0.f, dd = 0.f;
  for (int c = 0; c < CH; ++c) {
    float gv = bf2f(gr[c]);
    ss += gv * ldf(a_s, h * CH + c, isf32);
    dd += gv * ldf(a_d, h * CH + c, isf32);
  }
  asrc[tid] = ss;
  adst[tid] = dd;
}

// ---------------- per-dst softmax stats (max + sum only) ----------------
__global__ void softmax_stats(const int* __restrict__ rowptr, const int* __restrict__ csr_src,
                              const float* __restrict__ asrc, const float* __restrict__ adst,
                              float* __restrict__ maxv, float* __restrict__ sumv) {
  int tid = blockIdx.x * blockDim.x + threadIdx.x;
  if (tid >= N_NODES * HEADS) return;
  int n = tid >> 3, h = tid & 7;
  int start = rowptr[n], end = rowptr[n + 1];
  float ad = adst[tid];
  float m = -3.0e38f;
  for (int i = start; i < end; ++i) {
    float v = leakyf(asrc[csr_src[i] * HEADS + h] + ad);
    m = fmaxf(m, v);
  }
  float ssum = 0.f;
  for (int i = start; i < end; ++i) {
    float v = leakyf(asrc[csr_src[i] * HEADS + h] + ad);
    ssum += __expf(v - m);
  }
  maxv[tid] = m;
  sumv[tid] = ssum;
}

// ---------------- aggregation (gather per dst, alpha + residual recomputed) ----
// mean_mode=0: out[n,512] = bf16(elu(acc + bc) + (x@Wr + br)[n])
// mean_mode=1: out[n,64]  = bf16(elu(mean_h(acc) + bc))
__global__ __launch_bounds__(256) void aggregate(
    const int* __restrict__ rowptr, const int* __restrict__ csr_src,
    const float* __restrict__ asrc, const float* __restrict__ adst,
    const float* __restrict__ maxv, const float* __restrict__ sumv,
    const ushort_t* __restrict__ g,
    const void* __restrict__ x, const void* __restrict__ Wr,
    const void* __restrict__ br, const void* __restrict__ bc,
    ushort_t* __restrict__ out, int mean_mode, const int* __restrict__ dflag)
{
  int isf32 = *dflag;
  __shared__ float sx[3];
  int n = blockIdx.x;
  int t = threadIdx.x;
  if (t < 3) sx[t] = ldf(x, n * 3 + t, isf32);
  __syncthreads();

  int start = rowptr[n], end = rowptr[n + 1];
  int h0 = t >> 6;                 // heads h0 and h0+4
  int i0 = n * HEADS + h0;
  float ad0 = adst[i0],  ad1 = adst[i0 + 4];
  float m0  = maxv[i0],  m1  = maxv[i0 + 4];
  float is0 = 1.f / sumv[i0], is1 = 1.f / sumv[i0 + 4];

  float acc0 = 0.f, acc1 = 0.f;
  for (int i = start; i < end; ++i) {
    int s = csr_src[i];
    float e0 = __expf(leakyf(asrc[s * HEADS + h0]     + ad0) - m0);
    float e1 = __expf(leakyf(asrc[s * HEADS + h0 + 4] + ad1) - m1);
    acc0 += e0 * bf2f(g[(size_t)s * FDIM + t]);
    acc1 += e1 * bf2f(g[(size_t)s * FDIM + t + 256]);
  }
  acc0 *= is0;
  acc1 *= is1;

  if (!mean_mode) {
    float r0 = sx[0] * ldf(Wr, t, isf32)        + sx[1] * ldf(Wr, 512 + t, isf32)
             + sx[2] * ldf(Wr, 1024 + t, isf32) + ldf(br, t, isf32);
    float r1 = sx[0] * ldf(Wr, t + 256, isf32)  + sx[1] * ldf(Wr, 512 + t + 256, isf32)
             + sx[2] * ldf(Wr, 1024 + t + 256, isf32) + ldf(br, t + 256, isf32);
    out[(size_t)n * FDIM + t]       = f2bf(eluf(acc0 + ldf(bc, t, isf32)) + r0);
    out[(size_t)n * FDIM + t + 256] = f2bf(eluf(acc1 + ldf(bc, t + 256, isf32)) + r1);
  } else {
    __shared__ float red[256];
    red[t] = acc0 + acc1;          // heads {h0, h0+4} for channel t&63
    __syncthreads();
    if (t < 64) {
      float tot = red[t] + red[t + 64] + red[t + 128] + red[t + 192];
      out[(size_t)n * CH + t] = f2bf(eluf(tot * 0.125f + ldf(bc, t, isf32)));
    }
  }
}

// ---------------- node head ----------------
__global__ void node_head(const ushort_t* __restrict__ ne, const void* __restrict__ Wo,
                          const void* __restrict__ bo, void* __restrict__ out,
                          const int* __restrict__ dflag) {
  int isf32 = *dflag;
  int n = blockIdx.x * blockDim.x + threadIdx.x;
  if (n >= N_NODES) return;
  float a0 = 0.f, a1 = 0.f;
  for (int c = 0; c < 64; ++c) {
    float v = bf2f(ne[(size_t)n * 64 + c]);
    a0 += v * ldf(Wo, c * 2 + 0, isf32);
    a1 += v * ldf(Wo, c * 2 + 1, isf32);
  }
  stf(out, (size_t)n * 2 + 0, a0 + ldf(bo, 0, isf32), isf32);
  stf(out, (size_t)n * 2 + 1, a1 + ldf(bo, 1, isf32), isf32);
}

// ---------------- edge head: one wave per edge ----------------
__global__ __launch_bounds__(256) void edge_head(
    const int* __restrict__ ei, const float* __restrict__ asrc, const float* __restrict__ adst,
    const float* __restrict__ maxv, const float* __restrict__ sumv,
    const ushort_t* __restrict__ pq, const void* __restrict__ Wm1,
    const void* __restrict__ bm1, const void* __restrict__ Wm2,
    const void* __restrict__ bm2, void* __restrict__ out,
    const int* __restrict__ dflag)
{
  int isf32 = *dflag;
  __shared__ float sW1a[8 * 256];  // Wm1 rows 64..71 (alpha block)
  __shared__ float sW2[512];       // Wm2 [256,2]
  __shared__ float sb1[256];
  for (int i = threadIdx.x; i < 8 * 256; i += 256) sW1a[i] = ldf(Wm1, 64 * 256 + i, isf32);
  for (int i = threadIdx.x; i < 512; i += 256) sW2[i] = ldf(Wm2, i, isf32);
  sb1[threadIdx.x] = ldf(bm1, threadIdx.x, isf32);
  __syncthreads();

  int e = blockIdx.x * 4 + (threadIdx.x >> 6);
  int lane = threadIdx.x & 63;
  if (e >= N_EDGES) return;
  int s = ei[e], d = ei[N_EDGES + e];

  int h = lane & 7;
  float v = leakyf(asrc[s * HEADS + h] + adst[d * HEADS + h]);
  float a = __expf(v - maxv[d * HEADS + h]) / sumv[d * HEADS + h];
  float al[8];
  #pragma unroll
  for (int hh = 0; hh < 8; ++hh) al[hh] = __shfl(a, hh);

  int c0 = lane * 4;
  ushort4 pv = *(const ushort4*)(pq + (size_t)s * FDIM + c0);
  ushort4 qv = *(const ushort4*)(pq + (size_t)d * FDIM + 256 + c0);
  float p[4] = { bf2f(pv.x), bf2f(pv.y), bf2f(pv.z), bf2f(pv.w) };
  float q[4] = { bf2f(qv.x), bf2f(qv.y), bf2f(qv.z), bf2f(qv.w) };
  float acc0 = 0.f, acc1 = 0.f;
  #pragma unroll
  for (int j = 0; j < 4; ++j) {
    int c = c0 + j;
    float hv = p[j] + q[j] + sb1[c];
    #pragma unroll
    for (int hh = 0; hh < 8; ++hh) hv += al[hh] * sW1a[hh * 256 + c];
    hv = fmaxf(hv, 0.f);
    acc0 += hv * sW2[c * 2 + 0];
    acc1 += hv * sW2[c * 2 + 1];
  }
  #pragma unroll
  for (int off = 32; off > 0; off >>= 1) {
    acc0 += __shfl_down(acc0, off);
    acc1 += __shfl_down(acc1, off);
  }
  if (lane == 0) {
    stf(out, 100000 + (size_t)e * 2 + 0, acc0 + ldf(bm2, 0, isf32), isf32);
    stf(out, 100000 + (size_t)e * 2 + 1, acc1 + ldf(bm2, 1, isf32), isf32);
  }
}

// ---------------- launch ----------------
extern "C" void kernel_launch(void* const* d_in, const int* in_sizes, int n_in,
                              void* d_out, int out_size, void* d_ws, size_t ws_size,
                              hipStream_t stream) {
  const void* x   = d_in[0];
  const int*  ei  = (const int*)d_in[1];
  const void* Wn  = d_in[4];
  const void* bn  = d_in[5];
  const void* Wr  = d_in[6];
  const void* br  = d_in[7];
  const void* W1  = d_in[8];
  const void* as1 = d_in[9];
  const void* ad1 = d_in[10];
  const void* bc1 = d_in[11];
  const void* W2  = d_in[12];
  const void* as2 = d_in[13];
  const void* ad2 = d_in[14];
  const void* bc2 = d_in[15];
  const void* W3  = d_in[16];
  const void* as3 = d_in[17];
  const void* ad3 = d_in[18];
  const void* bc3 = d_in[19];
  const void* Wo  = d_in[20];
  const void* bo  = d_in[21];
  const void* Wm1 = d_in[22];
  const void* bm1 = d_in[23];
  const void* Wm2 = d_in[24];
  const void* bm2 = d_in[25];

  char* ws = (char*)d_ws;
  size_t off = 0;
  auto take = [&](size_t bytes) -> char* {
    char* p = ws + off;
    off += (bytes + 255) & ~(size_t)255;
    return p;
  };
  // total footprint ~119 MB
  ushort_t* h_bf   = (ushort_t*)take((size_t)N_NODES * 64 * 2);    // enc out / node_embedding
  ushort_t* g_bf   = (ushort_t*)take((size_t)N_NODES * FDIM * 2);  // gemm out / P|Q
  ushort_t* o_bf   = (ushort_t*)take((size_t)N_NODES * FDIM * 2);  // layer out
  float*    asrc   = (float*)take((size_t)N_NODES * HEADS * 4);
  float*    adst   = (float*)take((size_t)N_NODES * HEADS * 4);
  float*    maxv   = (float*)take((size_t)N_NODES * HEADS * 4);
  float*    sumv   = (float*)take((size_t)N_NODES * HEADS * 4);
  int*      rowptr = (int*)take((size_t)(N_NODES + 1) * 4);
  int*      csr_src= (int*)take((size_t)EPRIME * 4);
  int*      deg    = (int*)take((size_t)N_NODES * 4);
  int*      fillc  = (int*)take((size_t)N_NODES * 4);
  int*      dflag  = (int*)take(256);

  dim3 b256(256);
  const int MB = (N_NODES + 63) / 64;  // 782

  detect_dtype<<<dim3(1), dim3(64), 0, stream>>>(Wn, dflag);

  // CSR build
  init_deg<<<dim3((N_NODES + 255) / 256), b256, 0, stream>>>(deg, fillc);
  count_edges<<<dim3((N_EDGES + 255) / 256), b256, 0, stream>>>(ei, deg);
  scan64<<<dim3(1), dim3(64), 0, stream>>>(deg, rowptr);
  fill_csr<<<dim3((EPRIME + 255) / 256), b256, 0, stream>>>(ei, rowptr, fillc, csr_src);

  // node encoder
  encode_h<<<dim3((N_NODES * 64 + 255) / 256), b256, 0, stream>>>(x, Wn, bn, h_bf, dflag);

  dim3 nh_grid((N_NODES * HEADS + 255) / 256);

  // ---- GAT layer 1 (in: h_bf [N,64]) ----
  gemm64<<<dim3(MB, 8), b256, 0, stream>>>(h_bf, W1, 0, g_bf, N_NODES, 64, 512, 512, dflag);
  attn_coef<<<nh_grid, b256, 0, stream>>>(g_bf, as1, ad1, asrc, adst, dflag);
  softmax_stats<<<nh_grid, b256, 0, stream>>>(rowptr, csr_src, asrc, adst, maxv, sumv);
  aggregate<<<dim3(N_NODES), b256, 0, stream>>>(rowptr, csr_src, asrc, adst, maxv, sumv,
                                                g_bf, x, Wr, br, bc1, o_bf, 0, dflag);

  // ---- GAT layer 2 (in: o_bf [N,512]) ----
  gemm64<<<dim3(MB, 8), b256, 0, stream>>>(o_bf, W2, 0, g_bf, N_NODES, 512, 512, 512, dflag);
  attn_coef<<<nh_grid, b256, 0, stream>>>(g_bf, as2, ad2, asrc, adst, dflag);
  softmax_stats<<<nh_grid, b256, 0, stream>>>(rowptr, csr_src, asrc, adst, maxv, sumv);
  aggregate<<<dim3(N_NODES), b256, 0, stream>>>(rowptr, csr_src, asrc, adst, maxv, sumv,
                                                g_bf, x, Wr, br, bc2, o_bf, 0, dflag);

  // ---- GAT layer 3 (in: o_bf [N,512], mean over heads -> ne in h_bf) ----
  gemm64<<<dim3(MB, 8), b256, 0, stream>>>(o_bf, W3, 0, g_bf, N_NODES, 512, 512, 512, dflag);
  attn_coef<<<nh_grid, b256, 0, stream>>>(g_bf, as3, ad3, asrc, adst, dflag);
  softmax_stats<<<nh_grid, b256, 0, stream>>>(rowptr, csr_src, asrc, adst, maxv, sumv);
  aggregate<<<dim3(N_NODES), b256, 0, stream>>>(rowptr, csr_src, asrc, adst, maxv, sumv,
                                                g_bf, x, Wr, br, bc3, h_bf, 1, dflag);

  // ---- heads ----
  node_head<<<dim3((N_NODES + 255) / 256), b256, 0, stream>>>(h_bf, Wo, bo, d_out, dflag);
  // P = ne @ Wm1[rows 0..63]   -> g_bf cols 0..255
  // Q = ne @ Wm1[rows 72..135] -> g_bf cols 256..511  (row offset in ELEMENTS via boff)
  gemm64<<<dim3(MB, 4), b256, 0, stream>>>(h_bf, Wm1, 0,        g_bf,       N_NODES, 64, 256, 512, dflag);
  gemm64<<<dim3(MB, 4), b256, 0, stream>>>(h_bf, Wm1, 72 * 256, g_bf + 256, N_NODES, 64, 256, 512, dflag);
  edge_head<<<dim3(N_EDGES / 4), b256, 0, stream>>>(ei, asrc, adst, maxv, sumv, g_bf,
                                                    Wm1, bm1, Wm2, bm2, d_out, dflag);
}

// Round 4
// 2075.154 us; speedup vs baseline: 1.3140x; 1.3140x over previous
//
#include <hip/hip_runtime.h>
#include <hip/hip_bf16.h>
#include <math.h>

#define N_NODES 50000
#define N_EDGES 800000
#define EPRIME  (N_EDGES + N_NODES)   // edges + self loops
#define HEADS 8
#define CH 64
#define FDIM 512                       // HEADS*CH

typedef unsigned short ushort_t;
typedef __attribute__((ext_vector_type(8))) short bf16x8_t;  // 8 bf16 = 4 VGPRs
typedef __attribute__((ext_vector_type(4))) float f32x4_t;

__device__ __forceinline__ float bf2f(unsigned short u) {
  union { unsigned int i; float f; } v; v.i = ((unsigned int)u) << 16; return v.f;
}
__device__ __forceinline__ unsigned short f2bf(float f) {
  union { float f; unsigned int i; } v; v.f = f;
  unsigned int x = v.i;
  return (unsigned short)((x + 0x7fffu + ((x >> 16) & 1u)) >> 16);  // RNE
}
// dual-dtype load/store for RAW input tensors (dtype detected at runtime)
__device__ __forceinline__ float ldf(const void* p, size_t idx, int isf32) {
  return isf32 ? ((const float*)p)[idx] : bf2f(((const ushort_t*)p)[idx]);
}
__device__ __forceinline__ void stf(void* p, size_t idx, float v, int isf32) {
  if (isf32) ((float*)p)[idx] = v;
  else       ((ushort_t*)p)[idx] = f2bf(v);
}
__device__ __forceinline__ float leakyf(float v) { return v >= 0.f ? v : 0.2f * v; }
__device__ __forceinline__ float eluf(float v)   { return v > 0.f ? v : expm1f(v); }

// ---------------- dtype detector ----------------
__global__ void detect_dtype(const void* Wn, int* flag) {
  if (blockIdx.x == 0 && threadIdx.x == 0) {
    const ushort_t* u = (const ushort_t*)Wn;
    int extreme = 0;
    for (int i = 0; i < 384; ++i) {
      float v = fabsf(bf2f(u[i]));
      if (v != 0.f && (v > 16.f || v < 6.1e-5f)) extreme++;
    }
    *flag = (extreme >= 20) ? 1 : 0;
  }
}

// ---------------- weight convert: raw (f32|bf16) -> bf16 ws ----------------
__global__ void convert_bf16(const void* __restrict__ src, ushort_t* __restrict__ dst,
                             int count, const int* __restrict__ dflag) {
  int isf32 = *dflag;
  int i = blockIdx.x * blockDim.x + threadIdx.x;
  if (i < count) dst[i] = isf32 ? f2bf(((const float*)src)[i]) : ((const ushort_t*)src)[i];
}

// ---------------- CSR build ----------------
__global__ void init_deg(int* deg, int* fill) {
  int n = blockIdx.x * blockDim.x + threadIdx.x;
  if (n < N_NODES) { deg[n] = 1; fill[n] = 0; }   // 1 = self loop
}

__global__ void count_edges(const int* __restrict__ ei, int* deg) {
  int e = blockIdx.x * blockDim.x + threadIdx.x;
  if (e < N_EDGES) atomicAdd(&deg[ei[N_EDGES + e]], 1);
}

__global__ void scan64(const int* __restrict__ deg, int* __restrict__ rowptr) {
  const int CHUNK = (N_NODES + 63) / 64;   // 782
  int t = threadIdx.x;                      // 0..63, one wave
  int lo = t * CHUNK;
  int hi = lo + CHUNK; if (hi > N_NODES) hi = N_NODES;
  int s = 0;
  for (int i = lo; i < hi; ++i) s += deg[i];
  int inc = s;
  #pragma unroll
  for (int off = 1; off < 64; off <<= 1) {
    int u = __shfl_up(inc, off);
    if (t >= off) inc += u;
  }
  int run = inc - s;
  for (int i = lo; i < hi; ++i) { rowptr[i] = run; run += deg[i]; }
  if (t == 63) rowptr[N_NODES] = run;
}

__global__ void fill_csr(const int* __restrict__ ei, const int* __restrict__ rowptr,
                         int* fill, int* __restrict__ csr_src) {
  int e = blockIdx.x * blockDim.x + threadIdx.x;
  if (e >= EPRIME) return;
  int s, d;
  if (e < N_EDGES) { s = ei[e]; d = ei[N_EDGES + e]; }
  else             { s = d = e - N_EDGES; }
  int pos = rowptr[d] + atomicAdd(&fill[d], 1);
  csr_src[pos] = s;
}

// ---------------- node encoder ----------------
__global__ void encode_h(const void* __restrict__ x, const void* __restrict__ Wn,
                         const void* __restrict__ bn, ushort_t* __restrict__ h,
                         const int* __restrict__ dflag) {
  int isf32 = *dflag;
  int tid = blockIdx.x * blockDim.x + threadIdx.x;
  if (tid >= N_NODES * 64) return;
  int n = tid >> 6, j = tid & 63;
  float x0 = ldf(x, n * 3 + 0, isf32), x1 = ldf(x, n * 3 + 1, isf32), x2 = ldf(x, n * 3 + 2, isf32);
  float v = x0 * ldf(Wn, j, isf32) + x1 * ldf(Wn, 64 + j, isf32)
          + x2 * ldf(Wn, 128 + j, isf32) + ldf(bn, j, isf32);
  h[tid] = f2bf(v);
}

// ---------------- MFMA GEMM: C[M,*] = A[M,K] @ B[K,*] (all bf16, fp32 acc) ----
// 64x64 tile, 256 threads = 4 waves; wave w computes rows 16w..16w+15 x 64 cols.
// B staged transposed in LDS so B-fragments read as contiguous b128.
__global__ __launch_bounds__(256) void gemm_mfma(
    const ushort_t* __restrict__ A, const ushort_t* __restrict__ B,
    ushort_t* __restrict__ C, int M, int K, int ldb, int ldc)
{
  __shared__ __align__(16) ushort_t As[64][40];   // [row][k] pad 8 (80B stride)
  __shared__ __align__(16) ushort_t Bs[64][40];   // [col][k] transposed
  int tid = threadIdx.x;
  int wave = tid >> 6, lane = tid & 63;
  int row0 = blockIdx.x * 64, col0 = blockIdx.y * 64;
  f32x4_t acc0 = {0.f,0.f,0.f,0.f}, acc1 = acc0, acc2 = acc0, acc3 = acc0;

  int arow = tid >> 2;         // 0..63
  int ak   = (tid & 3) * 8;    // 0,8,16,24
  int bk   = tid >> 3;         // 0..31
  int bn   = (tid & 7) * 8;    // 0,8,..,56
  int fm = lane & 15, fq = lane >> 4;
  int agrow = row0 + arow;
  const ushort_t* aptr = A + (size_t)agrow * K + ak;

  for (int k0 = 0; k0 < K; k0 += 32) {
    ushort4 av0 = make_ushort4(0,0,0,0), av1 = make_ushort4(0,0,0,0);
    if (agrow < M) {
      av0 = *(const ushort4*)(aptr + k0);
      av1 = *(const ushort4*)(aptr + k0 + 4);
    }
    *(ushort4*)&As[arow][ak]     = av0;
    *(ushort4*)&As[arow][ak + 4] = av1;
    const ushort_t* bp = B + (size_t)(k0 + bk) * ldb + col0 + bn;
    ushort4 bv0 = *(const ushort4*)bp;
    ushort4 bv1 = *(const ushort4*)(bp + 4);
    Bs[bn + 0][bk] = bv0.x; Bs[bn + 1][bk] = bv0.y;
    Bs[bn + 2][bk] = bv0.z; Bs[bn + 3][bk] = bv0.w;
    Bs[bn + 4][bk] = bv1.x; Bs[bn + 5][bk] = bv1.y;
    Bs[bn + 6][bk] = bv1.z; Bs[bn + 7][bk] = bv1.w;
    __syncthreads();
    bf16x8_t af  = *(const bf16x8_t*)&As[16 * wave + fm][fq * 8];
    bf16x8_t bf0 = *(const bf16x8_t*)&Bs[fm][fq * 8];
    bf16x8_t bf1 = *(const bf16x8_t*)&Bs[16 + fm][fq * 8];
    bf16x8_t bf2 = *(const bf16x8_t*)&Bs[32 + fm][fq * 8];
    bf16x8_t bf3 = *(const bf16x8_t*)&Bs[48 + fm][fq * 8];
    acc0 = __builtin_amdgcn_mfma_f32_16x16x32_bf16(af, bf0, acc0, 0, 0, 0);
    acc1 = __builtin_amdgcn_mfma_f32_16x16x32_bf16(af, bf1, acc1, 0, 0, 0);
    acc2 = __builtin_amdgcn_mfma_f32_16x16x32_bf16(af, bf2, acc2, 0, 0, 0);
    acc3 = __builtin_amdgcn_mfma_f32_16x16x32_bf16(af, bf3, acc3, 0, 0, 0);
    __syncthreads();
  }
  // C/D layout: col = lane&15, row = (lane>>4)*4 + reg   [m89-verified]
  int crow = row0 + 16 * wave + fq * 4;
  #pragma unroll
  for (int r = 0; r < 4; ++r) {
    int row = crow + r;
    if (row < M) {
      size_t base = (size_t)row * ldc + col0 + fm;
      C[base]      = f2bf(acc0[r]);
      C[base + 16] = f2bf(acc1[r]);
      C[base + 32] = f2bf(acc2[r]);
      C[base + 48] = f2bf(acc3[r]);
    }
  }
}

// ---------------- attention coefficients ----------------
__global__ void attn_coef(const ushort_t* __restrict__ g, const void* __restrict__ a_s,
                          const void* __restrict__ a_d, float* __restrict__ asrc,
                          float* __restrict__ adst, const int* __restrict__ dflag) {
  int isf32 = *dflag;
  int tid = blockIdx.x * blockDim.x + threadIdx.x;
  if (tid >= N_NODES * HEADS) return;
  int n = tid >> 3, h = tid & 7;
  const ushort_t* gr = g + (size_t)n * FDIM + h * CH;
  float ss = 0.f, dd = 0.f;
  for (int c = 0; c < CH; ++c) {
    float gv = bf2f(gr[c]);
    ss += gv * ldf(a_s, h * CH + c, isf32);
    dd += gv * ldf(a_d, h * CH + c, isf32);
  }
  asrc[tid] = ss;
  adst[tid] = dd;
}

// ---------------- per-dst softmax stats (max + sum only) ----------------
__global__ void softmax_stats(const int* __restrict__ rowptr, const int* __restrict__ csr_src,
                              const float* __restrict__ asrc, const float* __restrict__ adst,
                              float* __restrict__ maxv, float* __restrict__ sumv) {
  int tid = blockIdx.x * blockDim.x + threadIdx.x;
  if (tid >= N_NODES * HEADS) return;
  int n = tid >> 3, h = tid & 7;
  int start = rowptr[n], end = rowptr[n + 1];
  float ad = adst[tid];
  float m = -3.0e38f;
  for (int i = start; i < end; ++i) {
    float v = leakyf(asrc[csr_src[i] * HEADS + h] + ad);
    m = fmaxf(m, v);
  }
  float ssum = 0.f;
  for (int i = start; i < end; ++i) {
    float v = leakyf(asrc[csr_src[i] * HEADS + h] + ad);
    ssum += __expf(v - m);
  }
  maxv[tid] = m;
  sumv[tid] = ssum;
}

// ---------------- aggregation (gather per dst, alpha + residual recomputed) ----
__global__ __launch_bounds__(256) void aggregate(
    const int* __restrict__ rowptr, const int* __restrict__ csr_src,
    const float* __restrict__ asrc, const float* __restrict__ adst,
    const float* __restrict__ maxv, const float* __restrict__ sumv,
    const ushort_t* __restrict__ g,
    const void* __restrict__ x, const void* __restrict__ Wr,
    const void* __restrict__ br, const void* __restrict__ bc,
    ushort_t* __restrict__ out, int mean_mode, const int* __restrict__ dflag)
{
  int isf32 = *dflag;
  __shared__ float sx[3];
  int n = blockIdx.x;
  int t = threadIdx.x;
  if (t < 3) sx[t] = ldf(x, n * 3 + t, isf32);
  __syncthreads();

  int start = rowptr[n], end = rowptr[n + 1];
  int h0 = t >> 6;                 // heads h0 and h0+4
  int i0 = n * HEADS + h0;
  float ad0 = adst[i0],  ad1 = adst[i0 + 4];
  float m0  = maxv[i0],  m1  = maxv[i0 + 4];
  float is0 = 1.f / sumv[i0], is1 = 1.f / sumv[i0 + 4];

  float acc0 = 0.f, acc1 = 0.f;
  for (int i = start; i < end; ++i) {
    int s = csr_src[i];
    float e0 = __expf(leakyf(asrc[s * HEADS + h0]     + ad0) - m0);
    float e1 = __expf(leakyf(asrc[s * HEADS + h0 + 4] + ad1) - m1);
    acc0 += e0 * bf2f(g[(size_t)s * FDIM + t]);
    acc1 += e1 * bf2f(g[(size_t)s * FDIM + t + 256]);
  }
  acc0 *= is0;
  acc1 *= is1;

  if (!mean_mode) {
    float r0 = sx[0] * ldf(Wr, t, isf32)        + sx[1] * ldf(Wr, 512 + t, isf32)
             + sx[2] * ldf(Wr, 1024 + t, isf32) + ldf(br, t, isf32);
    float r1 = sx[0] * ldf(Wr, t + 256, isf32)  + sx[1] * ldf(Wr, 512 + t + 256, isf32)
             + sx[2] * ldf(Wr, 1024 + t + 256, isf32) + ldf(br, t + 256, isf32);
    out[(size_t)n * FDIM + t]       = f2bf(eluf(acc0 + ldf(bc, t, isf32)) + r0);
    out[(size_t)n * FDIM + t + 256] = f2bf(eluf(acc1 + ldf(bc, t + 256, isf32)) + r1);
  } else {
    __shared__ float red[256];
    red[t] = acc0 + acc1;
    __syncthreads();
    if (t < 64) {
      float tot = red[t] + red[t + 64] + red[t + 128] + red[t + 192];
      out[(size_t)n * CH + t] = f2bf(eluf(tot * 0.125f + ldf(bc, t, isf32)));
    }
  }
}

// ---------------- node head ----------------
__global__ void node_head(const ushort_t* __restrict__ ne, const void* __restrict__ Wo,
                          const void* __restrict__ bo, void* __restrict__ out,
                          const int* __restrict__ dflag) {
  int isf32 = *dflag;
  int n = blockIdx.x * blockDim.x + threadIdx.x;
  if (n >= N_NODES) return;
  float a0 = 0.f, a1 = 0.f;
  for (int c = 0; c < 64; ++c) {
    float v = bf2f(ne[(size_t)n * 64 + c]);
    a0 += v * ldf(Wo, c * 2 + 0, isf32);
    a1 += v * ldf(Wo, c * 2 + 1, isf32);
  }
  stf(out, (size_t)n * 2 + 0, a0 + ldf(bo, 0, isf32), isf32);
  stf(out, (size_t)n * 2 + 1, a1 + ldf(bo, 1, isf32), isf32);
}

// ---------------- edge head v2: 32 edges per wave, MLP weights in registers ----
#define EPW 32
__global__ __launch_bounds__(256) void edge_head2(
    const int* __restrict__ ei, const float* __restrict__ asrc, const float* __restrict__ adst,
    const float* __restrict__ maxv, const float* __restrict__ sumv,
    const ushort_t* __restrict__ pq, const void* __restrict__ Wm1,
    const void* __restrict__ bm1, const void* __restrict__ Wm2,
    const void* __restrict__ bm2, void* __restrict__ out,
    const int* __restrict__ dflag)
{
  int isf32 = *dflag;
  int lane = threadIdx.x & 63;
  int c0 = lane * 4;
  // per-lane register copy of its 4 MLP channels
  float w1r[8][4], w2a[4], w2b[4], b1r[4];
  #pragma unroll
  for (int hh = 0; hh < 8; ++hh)
    #pragma unroll
    for (int j = 0; j < 4; ++j)
      w1r[hh][j] = ldf(Wm1, (64 + hh) * 256 + c0 + j, isf32);
  #pragma unroll
  for (int j = 0; j < 4; ++j) {
    w2a[j] = ldf(Wm2, (c0 + j) * 2 + 0, isf32);
    w2b[j] = ldf(Wm2, (c0 + j) * 2 + 1, isf32);
    b1r[j] = ldf(bm1, c0 + j, isf32);
  }
  float bo0 = ldf(bm2, 0, isf32), bo1 = ldf(bm2, 1, isf32);

  int wid = blockIdx.x * 4 + (threadIdx.x >> 6);
  int e0 = wid * EPW;
  int e1 = e0 + EPW; if (e1 > N_EDGES) e1 = N_EDGES;
  for (int e = e0; e < e1; ++e) {
    int s = ei[e], d = ei[N_EDGES + e];
    int h = lane & 7;
    float a = __expf(leakyf(asrc[s * HEADS + h] + adst[d * HEADS + h])
                     - maxv[d * HEADS + h]) / sumv[d * HEADS + h];
    float al[8];
    #pragma unroll
    for (int hh = 0; hh < 8; ++hh) al[hh] = __shfl(a, hh);

    ushort4 pv = *(const ushort4*)(pq + (size_t)s * FDIM + c0);
    ushort4 qv = *(const ushort4*)(pq + (size_t)d * FDIM + 256 + c0);
    float p[4] = { bf2f(pv.x), bf2f(pv.y), bf2f(pv.z), bf2f(pv.w) };
    float q[4] = { bf2f(qv.x), bf2f(qv.y), bf2f(qv.z), bf2f(qv.w) };
    float acc0 = 0.f, acc1 = 0.f;
    #pragma unroll
    for (int j = 0; j < 4; ++j) {
      float hv = p[j] + q[j] + b1r[j];
      #pragma unroll
      for (int hh = 0; hh < 8; ++hh) hv += al[hh] * w1r[hh][j];
      hv = fmaxf(hv, 0.f);
      acc0 += hv * w2a[j];
      acc1 += hv * w2b[j];
    }
    #pragma unroll
    for (int off = 32; off > 0; off >>= 1) {
      acc0 += __shfl_down(acc0, off);
      acc1 += __shfl_down(acc1, off);
    }
    if (lane == 0) {
      stf(out, 100000 + (size_t)e * 2 + 0, acc0 + bo0, isf32);
      stf(out, 100000 + (size_t)e * 2 + 1, acc1 + bo1, isf32);
    }
  }
}

// ---------------- launch ----------------
extern "C" void kernel_launch(void* const* d_in, const int* in_sizes, int n_in,
                              void* d_out, int out_size, void* d_ws, size_t ws_size,
                              hipStream_t stream) {
  const void* x   = d_in[0];
  const int*  ei  = (const int*)d_in[1];
  const void* Wn  = d_in[4];
  const void* bn  = d_in[5];
  const void* Wr  = d_in[6];
  const void* br  = d_in[7];
  const void* W1  = d_in[8];
  const void* as1 = d_in[9];
  const void* ad1 = d_in[10];
  const void* bc1 = d_in[11];
  const void* W2  = d_in[12];
  const void* as2 = d_in[13];
  const void* ad2 = d_in[14];
  const void* bc2 = d_in[15];
  const void* W3  = d_in[16];
  const void* as3 = d_in[17];
  const void* ad3 = d_in[18];
  const void* bc3 = d_in[19];
  const void* Wo  = d_in[20];
  const void* bo  = d_in[21];
  const void* Wm1 = d_in[22];
  const void* bm1 = d_in[23];
  const void* Wm2 = d_in[24];
  const void* bm2 = d_in[25];

  char* ws = (char*)d_ws;
  size_t off = 0;
  auto take = [&](size_t bytes) -> char* {
    char* p = ws + off;
    off += (bytes + 255) & ~(size_t)255;
    return p;
  };
  ushort_t* h_bf   = (ushort_t*)take((size_t)N_NODES * 64 * 2);    // enc out / node_embedding
  ushort_t* g_bf   = (ushort_t*)take((size_t)N_NODES * FDIM * 2);  // gemm out / P|Q
  ushort_t* o_bf   = (ushort_t*)take((size_t)N_NODES * FDIM * 2);  // layer out
  float*    asrc   = (float*)take((size_t)N_NODES * HEADS * 4);
  float*    adst   = (float*)take((size_t)N_NODES * HEADS * 4);
  float*    maxv   = (float*)take((size_t)N_NODES * HEADS * 4);
  float*    sumv   = (float*)take((size_t)N_NODES * HEADS * 4);
  int*      rowptr = (int*)take((size_t)(N_NODES + 1) * 4);
  int*      csr_src= (int*)take((size_t)EPRIME * 4);
  int*      deg    = (int*)take((size_t)N_NODES * 4);
  int*      fillc  = (int*)take((size_t)N_NODES * 4);
  int*      dflag  = (int*)take(256);
  ushort_t* wW1    = (ushort_t*)take((size_t)512 * 512 * 2);       // bf16 weights
  ushort_t* wW2    = (ushort_t*)take((size_t)512 * 512 * 2);
  ushort_t* wW3    = (ushort_t*)take((size_t)512 * 512 * 2);
  ushort_t* wWm1   = (ushort_t*)take((size_t)136 * 256 * 2);

  dim3 b256(256);
  const int MB = (N_NODES + 63) / 64;  // 782

  detect_dtype<<<dim3(1), dim3(64), 0, stream>>>(Wn, dflag);

  // weight conversion to bf16 (identity copy if already bf16)
  convert_bf16<<<dim3(1024), b256, 0, stream>>>(W1, wW1, 512 * 512, dflag);
  convert_bf16<<<dim3(1024), b256, 0, stream>>>(W2, wW2, 512 * 512, dflag);
  convert_bf16<<<dim3(1024), b256, 0, stream>>>(W3, wW3, 512 * 512, dflag);
  convert_bf16<<<dim3(136), b256, 0, stream>>>(Wm1, wWm1, 136 * 256, dflag);

  // CSR build
  init_deg<<<dim3((N_NODES + 255) / 256), b256, 0, stream>>>(deg, fillc);
  count_edges<<<dim3((N_EDGES + 255) / 256), b256, 0, stream>>>(ei, deg);
  scan64<<<dim3(1), dim3(64), 0, stream>>>(deg, rowptr);
  fill_csr<<<dim3((EPRIME + 255) / 256), b256, 0, stream>>>(ei, rowptr, fillc, csr_src);

  // node encoder
  encode_h<<<dim3((N_NODES * 64 + 255) / 256), b256, 0, stream>>>(x, Wn, bn, h_bf, dflag);

  dim3 nh_grid((N_NODES * HEADS + 255) / 256);

  // ---- GAT layer 1 (in: h_bf [N,64]) ----
  gemm_mfma<<<dim3(MB, 8), b256, 0, stream>>>(h_bf, wW1, g_bf, N_NODES, 64, 512, 512);
  attn_coef<<<nh_grid, b256, 0, stream>>>(g_bf, as1, ad1, asrc, adst, dflag);
  softmax_stats<<<nh_grid, b256, 0, stream>>>(rowptr, csr_src, asrc, adst, maxv, sumv);
  aggregate<<<dim3(N_NODES), b256, 0, stream>>>(rowptr, csr_src, asrc, adst, maxv, sumv,
                                                g_bf, x, Wr, br, bc1, o_bf, 0, dflag);

  // ---- GAT layer 2 (in: o_bf [N,512]) ----
  gemm_mfma<<<dim3(MB, 8), b256, 0, stream>>>(o_bf, wW2, g_bf, N_NODES, 512, 512, 512);
  attn_coef<<<nh_grid, b256, 0, stream>>>(g_bf, as2, ad2, asrc, adst, dflag);
  softmax_stats<<<nh_grid, b256, 0, stream>>>(rowptr, csr_src, asrc, adst, maxv, sumv);
  aggregate<<<dim3(N_NODES), b256, 0, stream>>>(rowptr, csr_src, asrc, adst, maxv, sumv,
                                                g_bf, x, Wr, br, bc2, o_bf, 0, dflag);

  // ---- GAT layer 3 (in: o_bf [N,512], mean over heads -> ne in h_bf) ----
  gemm_mfma<<<dim3(MB, 8), b256, 0, stream>>>(o_bf, wW3, g_bf, N_NODES, 512, 512, 512);
  attn_coef<<<nh_grid, b256, 0, stream>>>(g_bf, as3, ad3, asrc, adst, dflag);
  softmax_stats<<<nh_grid, b256, 0, stream>>>(rowptr, csr_src, asrc, adst, maxv, sumv);
  aggregate<<<dim3(N_NODES), b256, 0, stream>>>(rowptr, csr_src, asrc, adst, maxv, sumv,
                                                g_bf, x, Wr, br, bc3, h_bf, 1, dflag);

  // ---- heads ----
  node_head<<<dim3((N_NODES + 255) / 256), b256, 0, stream>>>(h_bf, Wo, bo, d_out, dflag);
  // P = ne @ Wm1[rows 0..63]   -> g_bf cols 0..255
  // Q = ne @ Wm1[rows 72..135] -> g_bf cols 256..511
  gemm_mfma<<<dim3(MB, 4), b256, 0, stream>>>(h_bf, wWm1,            g_bf,       N_NODES, 64, 256, 512);
  gemm_mfma<<<dim3(MB, 4), b256, 0, stream>>>(h_bf, wWm1 + 72 * 256, g_bf + 256, N_NODES, 64, 256, 512);
  edge_head2<<<dim3(N_EDGES / (EPW * 4)), b256, 0, stream>>>(ei, asrc, adst, maxv, sumv, g_bf,
                                                             Wm1, bm1, Wm2, bm2, d_out, dflag);
}

// Round 6
// 1714.283 us; speedup vs baseline: 1.5906x; 1.2105x over previous
//
#include <hip/hip_runtime.h>
#include <hip/hip_bf16.h>
#include <math.h>

#define N_NODES 50000
#define NPAD    50048                  // N_NODES rounded up to 128 (gemm tiles, no guards)
#define N_EDGES 800000
#define EPRIME  (N_EDGES + N_NODES)   // edges + self loops
#define HEADS 8
#define CH 64
#define FDIM 512                       // HEADS*CH

typedef unsigned short ushort_t;
typedef __attribute__((ext_vector_type(8))) short bf16x8_t;  // 8 bf16 = 4 VGPRs
typedef __attribute__((ext_vector_type(4))) float f32x4_t;

__device__ __forceinline__ float bf2f(unsigned short u) {
  union { unsigned int i; float f; } v; v.i = ((unsigned int)u) << 16; return v.f;
}
__device__ __forceinline__ unsigned short f2bf(float f) {
  union { float f; unsigned int i; } v; v.f = f;
  unsigned int x = v.i;
  return (unsigned short)((x + 0x7fffu + ((x >> 16) & 1u)) >> 16);  // RNE
}
__device__ __forceinline__ float ldf(const void* p, size_t idx, int isf32) {
  return isf32 ? ((const float*)p)[idx] : bf2f(((const ushort_t*)p)[idx]);
}
__device__ __forceinline__ void stf(void* p, size_t idx, float v, int isf32) {
  if (isf32) ((float*)p)[idx] = v;
  else       ((ushort_t*)p)[idx] = f2bf(v);
}
__device__ __forceinline__ float leakyf(float v) { return v >= 0.f ? v : 0.2f * v; }
__device__ __forceinline__ float eluf(float v)   { return v > 0.f ? v : expm1f(v); }

// async global->LDS, 16B per lane; LDS dest = wave-uniform base + lane*16
typedef const __attribute__((address_space(1))) unsigned int* gas1_t;
typedef __attribute__((address_space(3))) unsigned int* las3_t;
__device__ __forceinline__ void gll16(const ushort_t* g, ushort_t* l) {
  __builtin_amdgcn_global_load_lds((gas1_t)g, (las3_t)l, 16, 0, 0);
}

// ---------------- dtype detector ----------------
__global__ void detect_dtype(const void* Wn, int* flag) {
  if (blockIdx.x == 0 && threadIdx.x == 0) {
    const ushort_t* u = (const ushort_t*)Wn;
    int extreme = 0;
    for (int i = 0; i < 384; ++i) {
      float v = fabsf(bf2f(u[i]));
      if (v != 0.f && (v > 16.f || v < 6.1e-5f)) extreme++;
    }
    *flag = (extreme >= 20) ? 1 : 0;
  }
}

// ---------------- weight transpose-convert: dst[n*K+k] = src[(boff+k)*N + n] ----
__global__ void convert_wt(const void* __restrict__ src, ushort_t* __restrict__ dst,
                           int K, int N, int boff, const int* __restrict__ dflag) {
  int isf32 = *dflag;
  int tid = blockIdx.x * blockDim.x + threadIdx.x;
  if (tid >= N * K) return;
  int n = tid / K, k = tid % K;
  dst[tid] = f2bf(ldf(src, (size_t)(boff + k) * N + n, isf32));
}

// pack 6 attention vectors (3 layers x {a_src, a_dst}, 512 elems each) to bf16
__global__ void convert_att(const void* s1, const void* d1, const void* s2, const void* d2,
                            const void* s3, const void* d3, ushort_t* __restrict__ dst,
                            const int* __restrict__ dflag) {
  int isf32 = *dflag;
  int tid = blockIdx.x * blockDim.x + threadIdx.x;
  if (tid >= 6 * 512) return;
  int which = tid >> 9, idx = tid & 511;
  const void* p = which == 0 ? s1 : which == 1 ? d1 : which == 2 ? s2
                : which == 3 ? d2 : which == 4 ? s3 : d3;
  dst[tid] = f2bf(ldf(p, idx, isf32));
}

// ---------------- CSR build ----------------
__global__ void init_deg(int* deg, int* fill) {
  int n = blockIdx.x * blockDim.x + threadIdx.x;
  if (n < N_NODES) { deg[n] = 1; fill[n] = 0; }   // 1 = self loop
}

__global__ void count_edges(const int* __restrict__ ei, int* deg) {
  int e = blockIdx.x * blockDim.x + threadIdx.x;
  if (e < N_EDGES) atomicAdd(&deg[ei[N_EDGES + e]], 1);
}

__global__ void scan64(const int* __restrict__ deg, int* __restrict__ rowptr) {
  const int CHUNK = (N_NODES + 63) / 64;   // 782
  int t = threadIdx.x;
  int lo = t * CHUNK;
  int hi = lo + CHUNK; if (hi > N_NODES) hi = N_NODES;
  int s = 0;
  for (int i = lo; i < hi; ++i) s += deg[i];
  int inc = s;
  #pragma unroll
  for (int off = 1; off < 64; off <<= 1) {
    int u = __shfl_up(inc, off);
    if (t >= off) inc += u;
  }
  int run = inc - s;
  for (int i = lo; i < hi; ++i) { rowptr[i] = run; run += deg[i]; }
  if (t == 63) rowptr[N_NODES] = run;
}

__global__ void fill_csr(const int* __restrict__ ei, const int* __restrict__ rowptr,
                         int* fill, int* __restrict__ csr_src) {
  int e = blockIdx.x * blockDim.x + threadIdx.x;
  if (e >= EPRIME) return;
  int s, d;
  if (e < N_EDGES) { s = ei[e]; d = ei[N_EDGES + e]; }
  else             { s = d = e - N_EDGES; }
  int pos = rowptr[d] + atomicAdd(&fill[d], 1);
  csr_src[pos] = s;
}

// ---------------- node encoder ----------------
__global__ void encode_h(const void* __restrict__ x, const void* __restrict__ Wn,
                         const void* __restrict__ bn, ushort_t* __restrict__ h,
                         const int* __restrict__ dflag) {
  int isf32 = *dflag;
  int tid = blockIdx.x * blockDim.x + threadIdx.x;
  if (tid >= N_NODES * 64) return;
  int n = tid >> 6, j = tid & 63;
  float x0 = ldf(x, n * 3 + 0, isf32), x1 = ldf(x, n * 3 + 1, isf32), x2 = ldf(x, n * 3 + 2, isf32);
  float v = x0 * ldf(Wn, j, isf32) + x1 * ldf(Wn, 64 + j, isf32)
          + x2 * ldf(Wn, 128 + j, isf32) + ldf(bn, j, isf32);
  h[tid] = f2bf(v);
}

// ---------------- MFMA GEMM (m93/m97 structure): C = A @ BT^T ----------------
// A [NPAD][K] bf16 row-major; BT [N][K] bf16 (pre-transposed weights).
// 128x128 tile, 256 thr = 2x2 waves, each wave 4x4 frags of 16x16x32.
// Staging via global_load_lds width=16 into unpadded [128][32] LDS tiles.
__global__ __launch_bounds__(256) void gemm_bt(
    const ushort_t* __restrict__ A, const ushort_t* __restrict__ BT,
    ushort_t* __restrict__ C, int K, int ldc)
{
  __shared__ __align__(16) ushort_t As[128][32];
  __shared__ __align__(16) ushort_t Bs[128][32];
  int tid = threadIdx.x;
  int wave = tid >> 6, lane = tid & 63;
  int wr = wave >> 1, wc = wave & 1;
  int row0 = blockIdx.x * 128, col0 = blockIdx.y * 128;
  int fm = lane & 15, fq = lane >> 4;

  f32x4_t acc[4][4];
  #pragma unroll
  for (int i = 0; i < 4; ++i)
    #pragma unroll
    for (int j = 0; j < 4; ++j) acc[i][j] = (f32x4_t){0.f, 0.f, 0.f, 0.f};

  // staging: wave w covers tile rows 32w..32w+31; lane i -> row w*32 + i/4 (+16), k (i%4)*8
  int srow = wave * 32 + (lane >> 2);
  int skel = (lane & 3) * 8;
  const ushort_t* aG0 = A  + (size_t)(row0 + srow) * K + skel;
  const ushort_t* aG1 = A  + (size_t)(row0 + srow + 16) * K + skel;
  const ushort_t* bG0 = BT + (size_t)(col0 + srow) * K + skel;
  const ushort_t* bG1 = BT + (size_t)(col0 + srow + 16) * K + skel;
  ushort_t* aL0 = &As[wave * 32][0];
  ushort_t* aL1 = &As[wave * 32 + 16][0];
  ushort_t* bL0 = &Bs[wave * 32][0];
  ushort_t* bL1 = &Bs[wave * 32 + 16][0];

  for (int k0 = 0; k0 < K; k0 += 32) {
    gll16(aG0 + k0, aL0);
    gll16(aG1 + k0, aL1);
    gll16(bG0 + k0, bL0);
    gll16(bG1 + k0, bL1);
    __syncthreads();
    bf16x8_t af[4], bfr[4];
    #pragma unroll
    for (int i = 0; i < 4; ++i) af[i]  = *(const bf16x8_t*)&As[64 * wr + 16 * i + fm][fq * 8];
    #pragma unroll
    for (int j = 0; j < 4; ++j) bfr[j] = *(const bf16x8_t*)&Bs[64 * wc + 16 * j + fm][fq * 8];
    #pragma unroll
    for (int i = 0; i < 4; ++i)
      #pragma unroll
      for (int j = 0; j < 4; ++j)
        acc[i][j] = __builtin_amdgcn_mfma_f32_16x16x32_bf16(af[i], bfr[j], acc[i][j], 0, 0, 0);
    __syncthreads();
  }
  // C/D layout: col = lane&15, row = (lane>>4)*4 + reg  [verified in round-4 kernel]
  #pragma unroll
  for (int i = 0; i < 4; ++i) {
    int row = row0 + 64 * wr + 16 * i + fq * 4;
    #pragma unroll
    for (int j = 0; j < 4; ++j) {
      size_t base = (size_t)row * ldc + col0 + 64 * wc + 16 * j + fm;
      #pragma unroll
      for (int r = 0; r < 4; ++r)
        C[base + (size_t)r * ldc] = f2bf(acc[i][j][r]);
    }
  }
}

// ---------------- attention coefficients (vectorized, packed bf16 vectors) ----
__global__ void attn_coef(const ushort_t* __restrict__ g, const ushort_t* __restrict__ att,
                          float* __restrict__ asrc, float* __restrict__ adst) {
  int tid = blockIdx.x * blockDim.x + threadIdx.x;
  if (tid >= N_NODES * HEADS) return;
  int n = tid >> 3, h = tid & 7;
  const ushort_t* gr  = g + (size_t)n * FDIM + h * CH;
  const ushort_t* as_ = att + h * CH;
  const ushort_t* ad_ = att + 512 + h * CH;
  float ss = 0.f, dd = 0.f;
  #pragma unroll
  for (int c = 0; c < CH; c += 4) {
    ushort4 gv = *(const ushort4*)(gr + c);
    ushort4 av = *(const ushort4*)(as_ + c);
    ushort4 dv = *(const ushort4*)(ad_ + c);
    float g0 = bf2f(gv.x), g1 = bf2f(gv.y), g2 = bf2f(gv.z), g3 = bf2f(gv.w);
    ss += g0 * bf2f(av.x) + g1 * bf2f(av.y) + g2 * bf2f(av.z) + g3 * bf2f(av.w);
    dd += g0 * bf2f(dv.x) + g1 * bf2f(dv.y) + g2 * bf2f(dv.z) + g3 * bf2f(dv.w);
  }
  asrc[tid] = ss;
  adst[tid] = dd;
}

// ---------------- fused online-softmax aggregation (gather per dst) ----------
// mean_mode=0: out[n,512] = bf16(elu(acc + bc) + (x@Wr + br)[n])
// mean_mode=1: out[n,64]  = bf16(elu(mean_h(acc) + bc))
__global__ __launch_bounds__(256) void aggregate(
    const int* __restrict__ rowptr, const int* __restrict__ csr_src,
    const float* __restrict__ asrc, const float* __restrict__ adst,
    float* __restrict__ maxv, float* __restrict__ sumv,
    const ushort_t* __restrict__ g,
    const void* __restrict__ x, const void* __restrict__ Wr,
    const void* __restrict__ br, const void* __restrict__ bc,
    ushort_t* __restrict__ out, int mean_mode, const int* __restrict__ dflag)
{
  int isf32 = *dflag;
  __shared__ float sx[3];
  int n = blockIdx.x;
  int t = threadIdx.x;
  if (t < 3) sx[t] = ldf(x, n * 3 + t, isf32);
  __syncthreads();

  int start = rowptr[n], end = rowptr[n + 1];
  int h0 = t >> 6;                 // heads h0 and h0+4
  int i0 = n * HEADS + h0;
  float ad0 = adst[i0], ad1 = adst[i0 + 4];

  float m0 = -3.0e38f, l0 = 0.f, acc0 = 0.f;
  float m1 = -3.0e38f, l1 = 0.f, acc1 = 0.f;
  for (int i = start; i < end; ++i) {
    int s = csr_src[i];
    float e0 = leakyf(asrc[s * HEADS + h0]     + ad0);
    float e1 = leakyf(asrc[s * HEADS + h0 + 4] + ad1);
    if (e0 > m0) { float sc = __expf(m0 - e0); acc0 *= sc; l0 *= sc; m0 = e0; }  // wave-uniform
    if (e1 > m1) { float sc = __expf(m1 - e1); acc1 *= sc; l1 *= sc; m1 = e1; }
    float p0 = __expf(e0 - m0), p1 = __expf(e1 - m1);
    l0 += p0; l1 += p1;
    acc0 += p0 * bf2f(g[(size_t)s * FDIM + t]);
    acc1 += p1 * bf2f(g[(size_t)s * FDIM + t + 256]);
  }
  acc0 /= l0;
  acc1 /= l1;
  if ((t & 63) == 0) {            // one lane per (node,head) writes stats
    maxv[i0] = m0;     sumv[i0] = l0;
    maxv[i0 + 4] = m1; sumv[i0 + 4] = l1;
  }

  if (!mean_mode) {
    float r0 = sx[0] * ldf(Wr, t, isf32)        + sx[1] * ldf(Wr, 512 + t, isf32)
             + sx[2] * ldf(Wr, 1024 + t, isf32) + ldf(br, t, isf32);
    float r1 = sx[0] * ldf(Wr, t + 256, isf32)  + sx[1] * ldf(Wr, 512 + t + 256, isf32)
             + sx[2] * ldf(Wr, 1024 + t + 256, isf32) + ldf(br, t + 256, isf32);
    out[(size_t)n * FDIM + t]       = f2bf(eluf(acc0 + ldf(bc, t, isf32)) + r0);
    out[(size_t)n * FDIM + t + 256] = f2bf(eluf(acc1 + ldf(bc, t + 256, isf32)) + r1);
  } else {
    __shared__ float red[256];
    red[t] = acc0 + acc1;
    __syncthreads();
    if (t < 64) {
      float tot = red[t] + red[t + 64] + red[t + 128] + red[t + 192];
      out[(size_t)n * CH + t] = f2bf(eluf(tot * 0.125f + ldf(bc, t, isf32)));
    }
  }
}

// ---------------- node head ----------------
__global__ void node_head(const ushort_t* __restrict__ ne, const void* __restrict__ Wo,
                          const void* __restrict__ bo, void* __restrict__ out,
                          const int* __restrict__ dflag) {
  int isf32 = *dflag;
  int n = blockIdx.x * blockDim.x + threadIdx.x;
  if (n >= N_NODES) return;
  float a0 = 0.f, a1 = 0.f;
  for (int c = 0; c < 64; ++c) {
    float v = bf2f(ne[(size_t)n * 64 + c]);
    a0 += v * ldf(Wo, c * 2 + 0, isf32);
    a1 += v * ldf(Wo, c * 2 + 1, isf32);
  }
  stf(out, (size_t)n * 2 + 0, a0 + ldf(bo, 0, isf32), isf32);
  stf(out, (size_t)n * 2 + 1, a1 + ldf(bo, 1, isf32), isf32);
}

// ---------------- edge head: 32 edges per wave, MLP weights in registers ----
#define EPW 32
__global__ __launch_bounds__(256) void edge_head2(
    const int* __restrict__ ei, const float* __restrict__ asrc, const float* __restrict__ adst,
    const float* __restrict__ maxv, const float* __restrict__ sumv,
    const ushort_t* __restrict__ pq, const void* __restrict__ Wm1,
    const void* __restrict__ bm1, const void* __restrict__ Wm2,
    const void* __restrict__ bm2, void* __restrict__ out,
    const int* __restrict__ dflag)
{
  int isf32 = *dflag;
  int lane = threadIdx.x & 63;
  int c0 = lane * 4;
  float w1r[8][4], w2a[4], w2b[4], b1r[4];
  #pragma unroll
  for (int hh = 0; hh < 8; ++hh)
    #pragma unroll
    for (int j = 0; j < 4; ++j)
      w1r[hh][j] = ldf(Wm1, (64 + hh) * 256 + c0 + j, isf32);
  #pragma unroll
  for (int j = 0; j < 4; ++j) {
    w2a[j] = ldf(Wm2, (c0 + j) * 2 + 0, isf32);
    w2b[j] = ldf(Wm2, (c0 + j) * 2 + 1, isf32);
    b1r[j] = ldf(bm1, c0 + j, isf32);
  }
  float bo0 = ldf(bm2, 0, isf32), bo1 = ldf(bm2, 1, isf32);

  int wid = blockIdx.x * 4 + (threadIdx.x >> 6);
  int e0 = wid * EPW;
  int e1 = e0 + EPW; if (e1 > N_EDGES) e1 = N_EDGES;
  for (int e = e0; e < e1; ++e) {
    int s = ei[e], d = ei[N_EDGES + e];
    int h = lane & 7;
    float a = __expf(leakyf(asrc[s * HEADS + h] + adst[d * HEADS + h])
                     - maxv[d * HEADS + h]) / sumv[d * HEADS + h];
    float al[8];
    #pragma unroll
    for (int hh = 0; hh < 8; ++hh) al[hh] = __shfl(a, hh);

    ushort4 pv = *(const ushort4*)(pq + (size_t)s * FDIM + c0);
    ushort4 qv = *(const ushort4*)(pq + (size_t)d * FDIM + 256 + c0);
    float p[4] = { bf2f(pv.x), bf2f(pv.y), bf2f(pv.z), bf2f(pv.w) };
    float q[4] = { bf2f(qv.x), bf2f(qv.y), bf2f(qv.z), bf2f(qv.w) };
    float acc0 = 0.f, acc1 = 0.f;
    #pragma unroll
    for (int j = 0; j < 4; ++j) {
      float hv = p[j] + q[j] + b1r[j];
      #pragma unroll
      for (int hh = 0; hh < 8; ++hh) hv += al[hh] * w1r[hh][j];
      hv = fmaxf(hv, 0.f);
      acc0 += hv * w2a[j];
      acc1 += hv * w2b[j];
    }
    #pragma unroll
    for (int off = 32; off > 0; off >>= 1) {
      acc0 += __shfl_down(acc0, off);
      acc1 += __shfl_down(acc1, off);
    }
    if (lane == 0) {
      stf(out, 100000 + (size_t)e * 2 + 0, acc0 + bo0, isf32);
      stf(out, 100000 + (size_t)e * 2 + 1, acc1 + bo1, isf32);
    }
  }
}

// ---------------- launch ----------------
extern "C" void kernel_launch(void* const* d_in, const int* in_sizes, int n_in,
                              void* d_out, int out_size, void* d_ws, size_t ws_size,
                              hipStream_t stream) {
  const void* x   = d_in[0];
  const int*  ei  = (const int*)d_in[1];
  const void* Wn  = d_in[4];
  const void* bn  = d_in[5];
  const void* Wr  = d_in[6];
  const void* br  = d_in[7];
  const void* W1  = d_in[8];
  const void* as1 = d_in[9];
  const void* ad1 = d_in[10];
  const void* bc1 = d_in[11];
  const void* W2  = d_in[12];
  const void* as2 = d_in[13];
  const void* ad2 = d_in[14];
  const void* bc2 = d_in[15];
  const void* W3  = d_in[16];
  const void* as3 = d_in[17];
  const void* ad3 = d_in[18];
  const void* bc3 = d_in[19];
  const void* Wo  = d_in[20];
  const void* bo  = d_in[21];
  const void* Wm1 = d_in[22];
  const void* bm1 = d_in[23];
  const void* Wm2 = d_in[24];
  const void* bm2 = d_in[25];

  char* ws = (char*)d_ws;
  size_t off = 0;
  auto take = [&](size_t bytes) -> char* {
    char* p = ws + off;
    off += (bytes + 255) & ~(size_t)255;
    return p;
  };
  ushort_t* h_bf   = (ushort_t*)take((size_t)NPAD * 64 * 2);       // enc out / node_embedding
  ushort_t* g_bf   = (ushort_t*)take((size_t)NPAD * FDIM * 2);     // gemm out / P|Q
  ushort_t* o_bf   = (ushort_t*)take((size_t)NPAD * FDIM * 2);     // layer out
  float*    asrc   = (float*)take((size_t)N_NODES * HEADS * 4);
  float*    adst   = (float*)take((size_t)N_NODES * HEADS * 4);
  float*    maxv   = (float*)take((size_t)N_NODES * HEADS * 4);
  float*    sumv   = (float*)take((size_t)N_NODES * HEADS * 4);
  int*      rowptr = (int*)take((size_t)(N_NODES + 1) * 4);
  int*      csr_src= (int*)take((size_t)EPRIME * 4);
  int*      deg    = (int*)take((size_t)N_NODES * 4);
  int*      fillc  = (int*)take((size_t)N_NODES * 4);
  int*      dflag  = (int*)take(256);
  ushort_t* WT1    = (ushort_t*)take((size_t)512 * 64 * 2);        // W1^T  [512][64]
  ushort_t* WT2    = (ushort_t*)take((size_t)512 * 512 * 2);       // W2^T  [512][512]
  ushort_t* WT3    = (ushort_t*)take((size_t)512 * 512 * 2);       // W3^T  [512][512]
  ushort_t* WTP    = (ushort_t*)take((size_t)256 * 64 * 2);        // Wm1 rows 0..63 ^T
  ushort_t* WTQ    = (ushort_t*)take((size_t)256 * 64 * 2);        // Wm1 rows 72..135 ^T
  ushort_t* attv   = (ushort_t*)take((size_t)6 * 512 * 2);         // packed a_src/a_dst x3

  dim3 b256(256);
  const int MB = NPAD / 128;  // 391

  detect_dtype<<<dim3(1), dim3(64), 0, stream>>>(Wn, dflag);

  // weight conversion (transpose to [n][k], bf16)
  // FIX r6: W1 is [64,512] -> K=64, N=512 (was wrongly K=512 in r5, OOB reads)
  convert_wt<<<dim3(128),  b256, 0, stream>>>(W1, WT1, 64, 512, 0, dflag);
  convert_wt<<<dim3(1024), b256, 0, stream>>>(W2, WT2, 512, 512, 0, dflag);
  convert_wt<<<dim3(1024), b256, 0, stream>>>(W3, WT3, 512, 512, 0, dflag);
  convert_wt<<<dim3(64),   b256, 0, stream>>>(Wm1, WTP, 64, 256, 0, dflag);
  convert_wt<<<dim3(64),   b256, 0, stream>>>(Wm1, WTQ, 64, 256, 72, dflag);
  convert_att<<<dim3(12),  b256, 0, stream>>>(as1, ad1, as2, ad2, as3, ad3, attv, dflag);

  // CSR build
  init_deg<<<dim3((N_NODES + 255) / 256), b256, 0, stream>>>(deg, fillc);
  count_edges<<<dim3((N_EDGES + 255) / 256), b256, 0, stream>>>(ei, deg);
  scan64<<<dim3(1), dim3(64), 0, stream>>>(deg, rowptr);
  fill_csr<<<dim3((EPRIME + 255) / 256), b256, 0, stream>>>(ei, rowptr, fillc, csr_src);

  // node encoder
  encode_h<<<dim3((N_NODES * 64 + 255) / 256), b256, 0, stream>>>(x, Wn, bn, h_bf, dflag);

  dim3 nh_grid((N_NODES * HEADS + 255) / 256);

  // ---- GAT layer 1 (in: h_bf [NPAD,64]) ----
  gemm_bt<<<dim3(MB, 4), b256, 0, stream>>>(h_bf, WT1, g_bf, 64, 512);
  attn_coef<<<nh_grid, b256, 0, stream>>>(g_bf, attv, asrc, adst);
  aggregate<<<dim3(N_NODES), b256, 0, stream>>>(rowptr, csr_src, asrc, adst, maxv, sumv,
                                                g_bf, x, Wr, br, bc1, o_bf, 0, dflag);

  // ---- GAT layer 2 (in: o_bf [NPAD,512]) ----
  gemm_bt<<<dim3(MB, 4), b256, 0, stream>>>(o_bf, WT2, g_bf, 512, 512);
  attn_coef<<<nh_grid, b256, 0, stream>>>(g_bf, attv + 1024, asrc, adst);
  aggregate<<<dim3(N_NODES), b256, 0, stream>>>(rowptr, csr_src, asrc, adst, maxv, sumv,
                                                g_bf, x, Wr, br, bc2, o_bf, 0, dflag);

  // ---- GAT layer 3 (in: o_bf [NPAD,512], mean over heads -> ne in h_bf) ----
  gemm_bt<<<dim3(MB, 4), b256, 0, stream>>>(o_bf, WT3, g_bf, 512, 512);
  attn_coef<<<nh_grid, b256, 0, stream>>>(g_bf, attv + 2048, asrc, adst);
  aggregate<<<dim3(N_NODES), b256, 0, stream>>>(rowptr, csr_src, asrc, adst, maxv, sumv,
                                                g_bf, x, Wr, br, bc3, h_bf, 1, dflag);

  // ---- heads ----
  node_head<<<dim3((N_NODES + 255) / 256), b256, 0, stream>>>(h_bf, Wo, bo, d_out, dflag);
  // P = ne @ Wm1[rows 0..63]   -> g_bf cols 0..255
  // Q = ne @ Wm1[rows 72..135] -> g_bf cols 256..511
  gemm_bt<<<dim3(MB, 2), b256, 0, stream>>>(h_bf, WTP, g_bf,       64, 512);
  gemm_bt<<<dim3(MB, 2), b256, 0, stream>>>(h_bf, WTQ, g_bf + 256, 64, 512);
  edge_head2<<<dim3(N_EDGES / (EPW * 4)), b256, 0, stream>>>(ei, asrc, adst, maxv, sumv, g_bf,
                                                             Wm1, bm1, Wm2, bm2, d_out, dflag);
}